// Round 19
// baseline (1052.752 us; speedup 1.0000x reference)
//
#include <hip/hip_runtime.h>
#include <hip/hip_bf16.h>

#define B_     8
#define N_     1025
#define C_     3200
#define H_     25
#define D_     128
#define NQKV   (3 * C_)      // 9600 (segment offsets)
#define NQKVP  9728          // padded qkv row stride (38 * 256)
#define M_REAL (B_ * N_)     // 8200
#define M_PAD  8448          // 33 * 256
#define KVB    64
#define KPAD   1088          // 17 * 64, padded key stride of Vt
#define CPADW  3328          // 13 * 256, padded proj-weight rows

typedef __bf16 bf16x8 __attribute__((ext_vector_type(8)));
typedef short  short8 __attribute__((ext_vector_type(8)));
typedef float  f32x4  __attribute__((ext_vector_type(4)));
typedef unsigned int u32x4 __attribute__((ext_vector_type(4)));

__device__ __forceinline__ unsigned short f2bf(float f) {
    unsigned u = __builtin_bit_cast(unsigned, f);
    u += 0x7FFFu + ((u >> 16) & 1u);          // RNE; inputs are finite
    return (unsigned short)(u >> 16);
}
__device__ __forceinline__ float bf2f(unsigned short u) {
    unsigned v = ((unsigned)u) << 16;
    return __builtin_bit_cast(float, v);
}
__device__ __forceinline__ unsigned cvtpk_bf16(float lo, float hi) {
    unsigned r;
    asm("v_cvt_pk_bf16_f32 %0, %1, %2" : "=v"(r) : "v"(lo), "v"(hi));
    return r;
}
__device__ __forceinline__ float exp2_fast(float x) {
    return __builtin_amdgcn_exp2f(x);          // v_exp_f32: D = 2^S0
}
__device__ __forceinline__ void gload_lds16(const unsigned short* g, void* lds) {
    __builtin_amdgcn_global_load_lds(
        (const __attribute__((address_space(1))) void*)g,
        (__attribute__((address_space(3))) void*)lds, 16, 0, 0);
}

// ---------------- fp32 -> bf16 convert, with zero tail padding ----------------
__global__ __launch_bounds__(256) void convert_pad(const float* __restrict__ src,
                                                   unsigned short* __restrict__ dst,
                                                   long n_src, long n_tot) {
    long e = ((long)blockIdx.x * 256 + threadIdx.x) * 4;
    if (e >= n_tot) return;
    ushort4 o;
    if (e < n_src) {
        float4 v = *reinterpret_cast<const float4*>(src + e);
        o.x = f2bf(v.x); o.y = f2bf(v.y); o.z = f2bf(v.z); o.w = f2bf(v.w);
    } else {
        o.x = o.y = o.z = o.w = 0;
    }
    *reinterpret_cast<ushort4*>(dst + e) = o;
}

// ---------------- RMSNorm (full 3200-axis) in place on q / k.
// q additionally folds 1/sqrt(D) AND 1/ln2: attention softmax runs in exp2 domain.
__global__ __launch_bounds__(256) void rmsnorm_qk(unsigned short* __restrict__ qkv,
                                                  const float* __restrict__ qw,
                                                  const float* __restrict__ kw) {
    const int row = blockIdx.x;          // 0..8199
    const int seg = blockIdx.y;          // 0=q, 1=k
    unsigned short* p = qkv + (long)row * NQKVP + seg * C_;
    const float* w = seg ? kw : qw;
    const int t = threadIdx.x;
    const bool has2 = t < (400 - 256);   // 3200 elems = 400 x short8

    short8 v0 = reinterpret_cast<const short8*>(p)[t];
    short8 v1;
    if (has2) v1 = reinterpret_cast<const short8*>(p)[t + 256];

    float s = 0.f;
#pragma unroll
    for (int j = 0; j < 8; ++j) { float f = bf2f((unsigned short)v0[j]); s += f * f; }
    if (has2) {
#pragma unroll
        for (int j = 0; j < 8; ++j) { float f = bf2f((unsigned short)v1[j]); s += f * f; }
    }
#pragma unroll
    for (int m = 32; m; m >>= 1) s += __shfl_xor(s, m);
    __shared__ float red[4];
    if ((t & 63) == 0) red[t >> 6] = s;
    __syncthreads();
    float tot = red[0] + red[1] + red[2] + red[3];
    float scale = rsqrtf(tot * (1.f / C_) + 1e-6f);
    if (seg == 0) scale *= 0.08838834764831845f * 1.4426950408889634f;  // 1/sqrt(D) * 1/ln2

#pragma unroll
    for (int j = 0; j < 8; ++j) {
        float f = bf2f((unsigned short)v0[j]) * scale * w[t * 8 + j];
        v0[j] = (short)f2bf(f);
    }
    reinterpret_cast<short8*>(p)[t] = v0;
    if (has2) {
#pragma unroll
        for (int j = 0; j < 8; ++j) {
            float f = bf2f((unsigned short)v1[j]) * scale * w[(t + 256) * 8 + j];
            v1[j] = (short)f2bf(f);
        }
        reinterpret_cast<short8*>(p)[t + 256] = v1;
    }
}

// ---------------- pipelined NT GEMM: C = A(MxK) * B(NxK)^T, 256x256 tile, BK=32,
// 4-deep LDS ring, counted vmcnt (8/4/0), 2-way-free LDS swizzle ((row>>1)&3),
// XCD-column mapping. Measured optimum of this session (513us GEMM1, MfmaUtil 46%).
#define BKT 32
template <int FP32OUT>
__global__ __launch_bounds__(512) void gemm_pipe(const unsigned short* __restrict__ A,
                                                 const unsigned short* __restrict__ Bm,
                                                 unsigned short* __restrict__ Cb,
                                                 float* __restrict__ Cf,
                                                 const float* __restrict__ bias,
                                                 int K, int MT, int NT, int ldc,
                                                 int MStore, int NStore) {
    __shared__ unsigned short sA[4][256 * BKT];
    __shared__ unsigned short sB[4][256 * BKT];

    int bid = blockIdx.x;
    int xcd = bid & 7, pos = bid >> 3;
    int nstrips = NT >> 3;
    int fullpos = nstrips * MT;
    int mt, nt;
    if (pos < fullpos) {
        int strip = pos / MT;
        mt = pos - strip * MT;
        nt = strip * 8 + xcd;
    } else {
        int lin = bid - fullpos * 8;
        nt = nstrips * 8 + lin / MT;
        mt = lin - (lin / MT) * MT;
    }
    const int m0 = mt * 256, n0 = nt * 256;

    const int t = threadIdx.x, w = t >> 6, l = t & 63;
    const int lq = l & 15, lh = l >> 4;
    const int wr = w >> 2, wc = w & 3;

    const unsigned short* Ab = A + (long)m0 * K;
    const unsigned short* Bb = Bm + (long)n0 * K;
    const int nk = K / BKT;

    const int c0 = t, c1 = t + 512;
    const int r0 = c0 >> 2, s0 = (c0 & 3) ^ ((r0 >> 1) & 3);
    const int r1 = c1 >> 2, s1 = (c1 & 3) ^ ((r1 >> 1) & 3);

    f32x4 acc[8][4] = {};

    auto stage = [&](int tile) {   // 4 VMEM instructions per wave per call
        int k0 = tile * BKT;
        unsigned short* dA = sA[tile & 3];
        unsigned short* dB = sB[tile & 3];
        gload_lds16(Ab + (long)r0 * K + k0 + s0 * 8, (char*)dA + c0 * 16);
        gload_lds16(Ab + (long)r1 * K + k0 + s1 * 8, (char*)dA + c1 * 16);
        gload_lds16(Bb + (long)r0 * K + k0 + s0 * 8, (char*)dB + c0 * 16);
        gload_lds16(Bb + (long)r1 * K + k0 + s1 * 8, (char*)dB + c1 * 16);
    };

    stage(0); stage(1); stage(2);

    for (int tt = 0; tt < nk; ++tt) {
        if (tt + 2 < nk)      asm volatile("s_waitcnt vmcnt(8) lgkmcnt(0)" ::: "memory");
        else if (tt + 1 < nk) asm volatile("s_waitcnt vmcnt(4) lgkmcnt(0)" ::: "memory");
        else                  asm volatile("s_waitcnt vmcnt(0) lgkmcnt(0)" ::: "memory");
        __builtin_amdgcn_s_barrier();

        const unsigned short* bufA = sA[tt & 3];
        const unsigned short* bufB = sB[tt & 3];
        bf16x8 av[8], bv[4];
#pragma unroll
        for (int i = 0; i < 8; ++i) {
            int row = wr * 128 + i * 16 + lq;
            av[i] = *reinterpret_cast<const bf16x8*>(bufA + row * BKT + ((lh ^ ((row >> 1) & 3)) << 3));
        }
#pragma unroll
        for (int j = 0; j < 4; ++j) {
            int row = wc * 64 + j * 16 + lq;
            bv[j] = *reinterpret_cast<const bf16x8*>(bufB + row * BKT + ((lh ^ ((row >> 1) & 3)) << 3));
        }
        if (tt + 3 < nk) stage(tt + 3);

        __builtin_amdgcn_s_setprio(1);
#pragma unroll
        for (int i = 0; i < 8; ++i)
#pragma unroll
            for (int j = 0; j < 4; ++j)
                acc[i][j] = __builtin_amdgcn_mfma_f32_16x16x32_bf16(av[i], bv[j], acc[i][j], 0, 0, 0);
        __builtin_amdgcn_s_setprio(0);
    }

#pragma unroll
    for (int i = 0; i < 8; ++i) {
#pragma unroll
        for (int r2 = 0; r2 < 4; ++r2) {
            long grow = m0 + wr * 128 + i * 16 + lh * 4 + r2;
            if (FP32OUT && grow >= MStore) continue;
#pragma unroll
            for (int j = 0; j < 4; ++j) {
                int gcol = n0 + wc * 64 + j * 16 + lq;
                if (FP32OUT) {
                    if (gcol < NStore)
                        Cf[grow * ldc + gcol] = acc[i][j][r2] + bias[gcol];
                } else {
                    Cb[grow * ldc + gcol] = f2bf(acc[i][j][r2]);
                }
            }
        }
    }
}

// ---------------- V transpose: qkv v-segment [key][d] -> vtb [b][h][d][KPAD keys], zero-padded ----------------
__global__ __launch_bounds__(256) void v_transpose(const unsigned short* __restrict__ qkv,
                                                   unsigned short* __restrict__ vtb) {
    const int kt = blockIdx.x, h = blockIdx.y, b = blockIdx.z;
    const int t = threadIdx.x;
    __shared__ unsigned short tile[64][136];   // 272B row stride: 16B-aligned, bank-spread

    {
        int r = t >> 2, dq = (t & 3) * 32;
        int key = kt * 64 + r;
        int keyc = key < N_ ? key : N_ - 1;
        const unsigned short* src = qkv + ((long)(b * N_) + keyc) * NQKVP + 2 * C_ + h * D_ + dq;
        short8 a0 = *reinterpret_cast<const short8*>(src);
        short8 a1 = *reinterpret_cast<const short8*>(src + 8);
        short8 a2 = *reinterpret_cast<const short8*>(src + 16);
        short8 a3 = *reinterpret_cast<const short8*>(src + 24);
        if (key >= N_) { a0 = 0; a1 = 0; a2 = 0; a3 = 0; }
        *reinterpret_cast<short8*>(&tile[r][dq])      = a0;
        *reinterpret_cast<short8*>(&tile[r][dq + 8])  = a1;
        *reinterpret_cast<short8*>(&tile[r][dq + 16]) = a2;
        *reinterpret_cast<short8*>(&tile[r][dq + 24]) = a3;
    }
    __syncthreads();
    {
        int d = t >> 1, k0 = (t & 1) * 32;
        unsigned short* dst = vtb + ((long)(b * H_ + h) * D_ + d) * KPAD + kt * 64 + k0;
#pragma unroll
        for (int jj = 0; jj < 4; ++jj) {
            short8 g;
#pragma unroll
            for (int e = 0; e < 8; ++e) g[e] = (short)tile[k0 + jj * 8 + e][d];
            *reinterpret_cast<short8*>(dst + jj * 8) = g;
        }
    }
}

// ---------------- flash attention, swapped-QK design; softmax in exp2 domain.
// 8 waves x 32 q-rows = 256 q/block (r19): halves the redundant K/V staging passes
// (9 -> 5 q-tiles per (h,b)) and improves block-tail utilization. Per-wave compute
// code identical to the 4-wave version; staging covers 1024 slots with 512 threads
// (2 per thread), counted vmcnt scales 8->4. Waves with qbase >= N_ idle through
// barriers (wave-uniform guard), preserving the block sync structure.
__global__ __launch_bounds__(512, 2) void attn_fwd(const unsigned short* __restrict__ qkv,
                                                   const unsigned short* __restrict__ vtb,
                                                   unsigned short* __restrict__ outb) {
    const int qt = blockIdx.x, h = blockIdx.y, b = blockIdx.z;
    const int t = threadIdx.x, w = t >> 6, l = t & 63;
    const int lq = l & 15, lh = l >> 4;

    __shared__ unsigned short sK[2][KVB * D_];   // [key][128d], 16 slots/row, swizzled
    __shared__ unsigned short sV[2][D_ * KVB];   // [d][64k],    8 slots/row, swizzled

    const int qbase = qt * 256 + w * 32;
    const bool act = qbase < N_;                 // wave-uniform: any valid q-row in this wave

    // Q fragments (q pre-scaled in rmsnorm)
    bf16x8 qf[2][4];
#pragma unroll
    for (int qg = 0; qg < 2; ++qg) {
        int qrow = qbase + qg * 16 + lq; if (qrow > N_ - 1) qrow = N_ - 1;
        const unsigned short* qp = qkv + (long)(b * N_ + qrow) * NQKVP + h * D_;
#pragma unroll
        for (int ds = 0; ds < 4; ++ds)
            qf[qg][ds] = *reinterpret_cast<const bf16x8*>(qp + ds * 32 + lh * 8);
    }

    // staging source pointers (2 slots each of K and Vt per thread; 512 threads x 2 = 1024)
    const unsigned short* kp[2];
    const unsigned short* vp[2];
#pragma unroll
    for (int i = 0; i < 2; ++i) {
        int slot = i * 512 + t;
        { int r = slot >> 4, sd = (slot & 15) ^ (r & 7);
          kp[i] = qkv + ((long)(b * N_) + r) * NQKVP + C_ + h * D_ + sd * 8; }
        { int d = slot >> 3, sk = (slot & 7) ^ (d & 7);
          vp[i] = vtb + ((long)(b * H_ + h) * D_ + d) * KPAD + sk * 8; }
    }
    const long kvstep = 64L * NQKVP;

    auto stageK = [&](int tile, int buf) {       // 2 VMEM insts per wave
        char* dst = (char*)sK[buf];
        if (tile < 16) {
            long off = (long)tile * kvstep;
#pragma unroll
            for (int i = 0; i < 2; ++i) gload_lds16(kp[i] + off, dst + (i * 512 + t) * 16);
        } else {  // tail: all rows read key 1024 (invalid k's masked in softmax)
#pragma unroll
            for (int i = 0; i < 2; ++i) {
                int slot = i * 512 + t;
                int r = slot >> 4, sd = (slot & 15) ^ (r & 7);
                const unsigned short* p = qkv + ((long)(b * N_) + (N_ - 1)) * NQKVP + C_ + h * D_ + sd * 8;
                gload_lds16(p, dst + slot * 16);
            }
        }
    };
    auto stageV = [&](int tile, int buf) {       // 2 VMEM insts per wave; Vt zero-padded
        char* dst = (char*)sV[buf];
        long off = (long)tile * 64;
#pragma unroll
        for (int i = 0; i < 2; ++i) gload_lds16(vp[i] + off, dst + (i * 512 + t) * 16);
    };

    f32x4 o[2][8] = {};
    float m[2] = {-1e30f, -1e30f}, lsum[2] = {0.f, 0.f};

    stageK(0, 0); stageV(0, 0);

    for (int tt = 0; tt < 17; ++tt) {
        const int cur = tt & 1;
        if (tt < 16) { stageK(tt + 1, cur ^ 1); stageV(tt + 1, cur ^ 1); }
        // stage pair = 4 VMEM insts; keep tile tt+1's 4 in flight, drain tile tt.
        if (tt < 16) asm volatile("s_waitcnt vmcnt(4)" ::: "memory");
        else         asm volatile("s_waitcnt vmcnt(0)" ::: "memory");
        __builtin_amdgcn_s_barrier();

        if (act) {
            const unsigned short* bK = sK[cur];
            const unsigned short* bV = sV[cur];

            // S^T[k][q]: 4 chunks of 16 keys; lane holds k = c*16 + 4*lh + r, q = lq
            f32x4 s[2][4] = {};
#pragma unroll
            for (int c = 0; c < 4; ++c) {
                bf16x8 kf[4];
#pragma unroll
                for (int ds = 0; ds < 4; ++ds)
                    kf[ds] = *reinterpret_cast<const bf16x8*>(
                        bK + (c * 16 + lq) * D_ + (((ds << 2) + lh) ^ (lq & 7)) * 8);
                __builtin_amdgcn_s_setprio(1);
#pragma unroll
                for (int qg = 0; qg < 2; ++qg)
#pragma unroll
                    for (int ds = 0; ds < 4; ++ds)
                        s[qg][c] = __builtin_amdgcn_mfma_f32_16x16x32_bf16(kf[ds], qf[qg][ds], s[qg][c], 0, 0, 0);
                __builtin_amdgcn_s_setprio(0);
            }
            if (tt == 16) {   // mask keys >= 1025 (only k_local 0 valid)
#pragma unroll
                for (int c = 0; c < 4; ++c)
#pragma unroll
                    for (int r = 0; r < 4; ++r)
                        if (c * 16 + 4 * lh + r != 0) { s[0][c][r] = -1e30f; s[1][c][r] = -1e30f; }
            }

            bf16x8 pa[2][2];
#pragma unroll
            for (int qg = 0; qg < 2; ++qg) {
                float mx = s[qg][0][0];
#pragma unroll
                for (int c = 0; c < 4; ++c)
#pragma unroll
                    for (int r = 0; r < 4; ++r) mx = fmaxf(mx, s[qg][c][r]);
                mx = fmaxf(mx, __shfl_xor(mx, 16));
                mx = fmaxf(mx, __shfl_xor(mx, 32));
                if (__any(mx - m[qg] > 11.5416f)) {   // T13 defer-rescale (8/ln2, exp2 domain)
                    float mnew = fmaxf(m[qg], mx);
                    float corr = exp2_fast(m[qg] - mnew);
                    lsum[qg] *= corr;
#pragma unroll
                    for (int r = 0; r < 4; ++r) {
                        float co = __shfl(corr, lh * 4 + r);
#pragma unroll
                        for (int nf = 0; nf < 8; ++nf) o[qg][nf][r] *= co;
                    }
                    m[qg] = mnew;
                }
                float p[4][4]; float rs = 0.f;
#pragma unroll
                for (int c = 0; c < 4; ++c)
#pragma unroll
                    for (int r = 0; r < 4; ++r) {
                        p[c][r] = exp2_fast(s[qg][c][r] - m[qg]);
                        rs += p[c][r];
                    }
                rs += __shfl_xor(rs, 16);
                rs += __shfl_xor(rs, 32);
                lsum[qg] += rs;
#pragma unroll
                for (int h2 = 0; h2 < 2; ++h2) {
                    unsigned A0 = cvtpk_bf16(p[2 * h2][0], p[2 * h2][1]);
                    unsigned A1 = cvtpk_bf16(p[2 * h2][2], p[2 * h2][3]);
                    unsigned B0 = cvtpk_bf16(p[2 * h2 + 1][0], p[2 * h2 + 1][1]);
                    unsigned B1 = cvtpk_bf16(p[2 * h2 + 1][2], p[2 * h2 + 1][3]);
                    const bool lo2 = lh < 2, odd = lh & 1;
                    unsigned x16_0 = __shfl_xor(lo2 ? A0 : B0, 16);
                    unsigned x16_1 = __shfl_xor(lo2 ? A1 : B1, 16);
                    unsigned x32_0 = __shfl_xor(lo2 ? B0 : A0, 32);
                    unsigned x32_1 = __shfl_xor(lo2 ? B1 : A1, 32);
                    unsigned x48_0 = __shfl_xor(odd ? B0 : A0, 48);
                    unsigned x48_1 = __shfl_xor(odd ? B1 : A1, 48);
                    unsigned w0 = lh == 0 ? A0 : lh == 1 ? x48_0 : lh == 2 ? x32_0 : x16_0;
                    unsigned w1 = lh == 0 ? A1 : lh == 1 ? x48_1 : lh == 2 ? x32_1 : x16_1;
                    unsigned w2 = lh == 0 ? x16_0 : lh == 1 ? x32_0 : lh == 2 ? x48_0 : B0;
                    unsigned w3 = lh == 0 ? x16_1 : lh == 1 ? x32_1 : lh == 2 ? x48_1 : B1;
                    u32x4 wv = {w0, w1, w2, w3};
                    pa[qg][h2] = __builtin_bit_cast(bf16x8, wv);
                }
            }

            // PV: o[q][d] += P[q][k] * Vt[d][k]
#pragma unroll
            for (int h2 = 0; h2 < 2; ++h2) {
                bf16x8 vf[8];
#pragma unroll
                for (int nf = 0; nf < 8; ++nf)
                    vf[nf] = *reinterpret_cast<const bf16x8*>(
                        bV + (nf * 16 + lq) * KVB + (((h2 << 2) + lh) ^ (lq & 7)) * 8);
                __builtin_amdgcn_s_setprio(1);
#pragma unroll
                for (int qg = 0; qg < 2; ++qg)
#pragma unroll
                    for (int nf = 0; nf < 8; ++nf)
                        o[qg][nf] = __builtin_amdgcn_mfma_f32_16x16x32_bf16(pa[qg][h2], vf[nf], o[qg][nf], 0, 0, 0);
                __builtin_amdgcn_s_setprio(0);
            }
        }
        __builtin_amdgcn_s_barrier();
    }

    // epilogue: normalize by lsum and store
    if (act) {
#pragma unroll
        for (int qg = 0; qg < 2; ++qg) {
            float linv = 1.f / lsum[qg];
#pragma unroll
            for (int r = 0; r < 4; ++r) {
                float li = __shfl(linv, lh * 4 + r);
                int row = qbase + qg * 16 + 4 * lh + r;
                if (row < N_) {
                    unsigned short* dst = outb + (long)(b * N_ + row) * C_ + h * D_ + lq;
#pragma unroll
                    for (int nf = 0; nf < 8; ++nf)
                        dst[nf * 16] = f2bf(o[qg][nf][r] * li);
                }
            }
        }
    }
}

extern "C" void kernel_launch(void* const* d_in, const int* in_sizes, int n_in,
                              void* d_out, int out_size, void* d_ws, size_t ws_size,
                              hipStream_t stream) {
    (void)in_sizes; (void)n_in; (void)out_size; (void)ws_size;
    const float* x   = (const float*)d_in[0];
    const float* wq  = (const float*)d_in[1];
    const float* qnw = (const float*)d_in[2];
    const float* knw = (const float*)d_in[3];
    const float* wp  = (const float*)d_in[4];
    const float* bp  = (const float*)d_in[5];
    float* out = (float*)d_out;

    // workspace layout (bf16 buffers), ~356 MB
    unsigned short* xb    = (unsigned short*)d_ws;                 // M_PAD x C
    unsigned short* wqb   = xb   + (size_t)M_PAD * C_;             // NQKVP x C (dead after GEMM1)
    unsigned short* wpb   = wqb  + (size_t)NQKVP * C_;             // CPADW x C (rows >= 3200 zero)
    unsigned short* qkvb  = wpb  + (size_t)CPADW * C_;             // M_PAD x NQKVP
    unsigned short* attnb = qkvb + (size_t)M_PAD * NQKVP;          // M_PAD x C
    unsigned short* vtb   = wqb;   // V^T [B][H][D][KPAD] = 55.7 MB, aliases dead wqb (62.3 MB)

    auto cvt = [&](const float* s, unsigned short* d, long nsrc, long ntot) {
        int blocks = (int)((ntot / 4 + 255) / 256);
        convert_pad<<<blocks, 256, 0, stream>>>(s, d, nsrc, ntot);
    };
    cvt(x,  xb,  (long)M_REAL * C_, (long)M_PAD * C_);
    cvt(wq, wqb, (long)NQKV * C_,   (long)NQKVP * C_);
    cvt(wp, wpb, (long)C_ * C_,     (long)CPADW * C_);
    cvt(x, attnb + (size_t)M_REAL * C_, 0, (long)(M_PAD - M_REAL) * C_);  // zero pad rows

    // GEMM1: qkv = x * w_qkv^T  (M=8448, Ncols=9728, K=3200)
    gemm_pipe<0><<<(M_PAD / 256) * (NQKVP / 256), 512, 0, stream>>>(
        xb, wqb, qkvb, nullptr, nullptr, C_, M_PAD / 256, NQKVP / 256, NQKVP, M_PAD, NQKVP);

    rmsnorm_qk<<<dim3(M_REAL, 2), 256, 0, stream>>>(qkvb, qnw, knw);

    v_transpose<<<dim3(17, H_, B_), 256, 0, stream>>>(qkvb, vtb);

    attn_fwd<<<dim3(5, H_, B_), 512, 0, stream>>>(qkvb, vtb, attnb);

    // GEMM2: out = attn * w_proj^T + b  (M=8448->8200, Ncols=3328->3200, K=3200)
    gemm_pipe<1><<<(M_PAD / 256) * (CPADW / 256), 512, 0, stream>>>(
        attnb, wpb, nullptr, out, bp, C_, M_PAD / 256, CPADW / 256, C_, M_REAL, C_);
}

// Round 20
// 1045.803 us; speedup vs baseline: 1.0066x; 1.0066x over previous
//
#include <hip/hip_runtime.h>
#include <hip/hip_bf16.h>

#define B_     8
#define N_     1025
#define C_     3200
#define H_     25
#define D_     128
#define NQKV   (3 * C_)      // 9600 (segment offsets)
#define NQKVP  9728          // padded qkv row stride (38 * 256)
#define M_REAL (B_ * N_)     // 8200
#define M_PAD  8448          // 33 * 256
#define KVB    64
#define KPAD   1088          // 17 * 64, padded key stride of Vt
#define CPADW  3328          // 13 * 256, padded proj-weight rows

typedef __bf16 bf16x8 __attribute__((ext_vector_type(8)));
typedef short  short8 __attribute__((ext_vector_type(8)));
typedef float  f32x4  __attribute__((ext_vector_type(4)));
typedef unsigned int u32x4 __attribute__((ext_vector_type(4)));

__device__ __forceinline__ unsigned short f2bf(float f) {
    unsigned u = __builtin_bit_cast(unsigned, f);
    u += 0x7FFFu + ((u >> 16) & 1u);          // RNE; inputs are finite
    return (unsigned short)(u >> 16);
}
__device__ __forceinline__ float bf2f(unsigned short u) {
    unsigned v = ((unsigned)u) << 16;
    return __builtin_bit_cast(float, v);
}
__device__ __forceinline__ unsigned cvtpk_bf16(float lo, float hi) {
    unsigned r;
    asm("v_cvt_pk_bf16_f32 %0, %1, %2" : "=v"(r) : "v"(lo), "v"(hi));
    return r;
}
__device__ __forceinline__ float exp2_fast(float x) {
    return __builtin_amdgcn_exp2f(x);          // v_exp_f32: D = 2^S0
}
__device__ __forceinline__ void gload_lds16(const unsigned short* g, void* lds) {
    __builtin_amdgcn_global_load_lds(
        (const __attribute__((address_space(1))) void*)g,
        (__attribute__((address_space(3))) void*)lds, 16, 0, 0);
}

// ---------------- fp32 -> bf16 convert, with zero tail padding ----------------
__global__ __launch_bounds__(256) void convert_pad(const float* __restrict__ src,
                                                   unsigned short* __restrict__ dst,
                                                   long n_src, long n_tot) {
    long e = ((long)blockIdx.x * 256 + threadIdx.x) * 4;
    if (e >= n_tot) return;
    ushort4 o;
    if (e < n_src) {
        float4 v = *reinterpret_cast<const float4*>(src + e);
        o.x = f2bf(v.x); o.y = f2bf(v.y); o.z = f2bf(v.z); o.w = f2bf(v.w);
    } else {
        o.x = o.y = o.z = o.w = 0;
    }
    *reinterpret_cast<ushort4*>(dst + e) = o;
}

// ---------------- RMSNorm (full 3200-axis) in place on q / k.
// q additionally folds 1/sqrt(D) AND 1/ln2: attention softmax runs in exp2 domain.
__global__ __launch_bounds__(256) void rmsnorm_qk(unsigned short* __restrict__ qkv,
                                                  const float* __restrict__ qw,
                                                  const float* __restrict__ kw) {
    const int row = blockIdx.x;          // 0..8199
    const int seg = blockIdx.y;          // 0=q, 1=k
    unsigned short* p = qkv + (long)row * NQKVP + seg * C_;
    const float* w = seg ? kw : qw;
    const int t = threadIdx.x;
    const bool has2 = t < (400 - 256);   // 3200 elems = 400 x short8

    short8 v0 = reinterpret_cast<const short8*>(p)[t];
    short8 v1;
    if (has2) v1 = reinterpret_cast<const short8*>(p)[t + 256];

    float s = 0.f;
#pragma unroll
    for (int j = 0; j < 8; ++j) { float f = bf2f((unsigned short)v0[j]); s += f * f; }
    if (has2) {
#pragma unroll
        for (int j = 0; j < 8; ++j) { float f = bf2f((unsigned short)v1[j]); s += f * f; }
    }
#pragma unroll
    for (int m = 32; m; m >>= 1) s += __shfl_xor(s, m);
    __shared__ float red[4];
    if ((t & 63) == 0) red[t >> 6] = s;
    __syncthreads();
    float tot = red[0] + red[1] + red[2] + red[3];
    float scale = rsqrtf(tot * (1.f / C_) + 1e-6f);
    if (seg == 0) scale *= 0.08838834764831845f * 1.4426950408889634f;  // 1/sqrt(D) * 1/ln2

#pragma unroll
    for (int j = 0; j < 8; ++j) {
        float f = bf2f((unsigned short)v0[j]) * scale * w[t * 8 + j];
        v0[j] = (short)f2bf(f);
    }
    reinterpret_cast<short8*>(p)[t] = v0;
    if (has2) {
#pragma unroll
        for (int j = 0; j < 8; ++j) {
            float f = bf2f((unsigned short)v1[j]) * scale * w[(t + 256) * 8 + j];
            v1[j] = (short)f2bf(f);
        }
        reinterpret_cast<short8*>(p)[t + 256] = v1;
    }
}

// ---------------- pipelined NT GEMM: C = A(MxK) * B(NxK)^T, 256x256 tile, BK=32,
// 4-deep LDS ring, counted vmcnt (8/4/0), 2-way-free LDS swizzle ((row>>1)&3),
// XCD-column mapping. Measured optimum of this session (511us GEMM1, MfmaUtil 46%,
// 0 bank conflicts). Structural ceiling: LDS 128KB/tile @256B/cy = 512cy vs MFMA
// 310cy -> ~60% max; schedule refinements to close 46->60 all regressed (r9/r12/r15),
// occupancy excluded by VGPR (r13 spill), smaller tiles lower the LDS ceiling.
#define BKT 32
template <int FP32OUT>
__global__ __launch_bounds__(512) void gemm_pipe(const unsigned short* __restrict__ A,
                                                 const unsigned short* __restrict__ Bm,
                                                 unsigned short* __restrict__ Cb,
                                                 float* __restrict__ Cf,
                                                 const float* __restrict__ bias,
                                                 int K, int MT, int NT, int ldc,
                                                 int MStore, int NStore) {
    __shared__ unsigned short sA[4][256 * BKT];
    __shared__ unsigned short sB[4][256 * BKT];

    int bid = blockIdx.x;
    int xcd = bid & 7, pos = bid >> 3;
    int nstrips = NT >> 3;
    int fullpos = nstrips * MT;
    int mt, nt;
    if (pos < fullpos) {
        int strip = pos / MT;
        mt = pos - strip * MT;
        nt = strip * 8 + xcd;
    } else {
        int lin = bid - fullpos * 8;
        nt = nstrips * 8 + lin / MT;
        mt = lin - (lin / MT) * MT;
    }
    const int m0 = mt * 256, n0 = nt * 256;

    const int t = threadIdx.x, w = t >> 6, l = t & 63;
    const int lq = l & 15, lh = l >> 4;
    const int wr = w >> 2, wc = w & 3;

    const unsigned short* Ab = A + (long)m0 * K;
    const unsigned short* Bb = Bm + (long)n0 * K;
    const int nk = K / BKT;

    const int c0 = t, c1 = t + 512;
    const int r0 = c0 >> 2, s0 = (c0 & 3) ^ ((r0 >> 1) & 3);
    const int r1 = c1 >> 2, s1 = (c1 & 3) ^ ((r1 >> 1) & 3);

    f32x4 acc[8][4] = {};

    auto stage = [&](int tile) {   // 4 VMEM instructions per wave per call
        int k0 = tile * BKT;
        unsigned short* dA = sA[tile & 3];
        unsigned short* dB = sB[tile & 3];
        gload_lds16(Ab + (long)r0 * K + k0 + s0 * 8, (char*)dA + c0 * 16);
        gload_lds16(Ab + (long)r1 * K + k0 + s1 * 8, (char*)dA + c1 * 16);
        gload_lds16(Bb + (long)r0 * K + k0 + s0 * 8, (char*)dB + c0 * 16);
        gload_lds16(Bb + (long)r1 * K + k0 + s1 * 8, (char*)dB + c1 * 16);
    };

    stage(0); stage(1); stage(2);

    for (int tt = 0; tt < nk; ++tt) {
        if (tt + 2 < nk)      asm volatile("s_waitcnt vmcnt(8) lgkmcnt(0)" ::: "memory");
        else if (tt + 1 < nk) asm volatile("s_waitcnt vmcnt(4) lgkmcnt(0)" ::: "memory");
        else                  asm volatile("s_waitcnt vmcnt(0) lgkmcnt(0)" ::: "memory");
        __builtin_amdgcn_s_barrier();

        const unsigned short* bufA = sA[tt & 3];
        const unsigned short* bufB = sB[tt & 3];
        bf16x8 av[8], bv[4];
#pragma unroll
        for (int i = 0; i < 8; ++i) {
            int row = wr * 128 + i * 16 + lq;
            av[i] = *reinterpret_cast<const bf16x8*>(bufA + row * BKT + ((lh ^ ((row >> 1) & 3)) << 3));
        }
#pragma unroll
        for (int j = 0; j < 4; ++j) {
            int row = wc * 64 + j * 16 + lq;
            bv[j] = *reinterpret_cast<const bf16x8*>(bufB + row * BKT + ((lh ^ ((row >> 1) & 3)) << 3));
        }
        if (tt + 3 < nk) stage(tt + 3);

        __builtin_amdgcn_s_setprio(1);
#pragma unroll
        for (int i = 0; i < 8; ++i)
#pragma unroll
            for (int j = 0; j < 4; ++j)
                acc[i][j] = __builtin_amdgcn_mfma_f32_16x16x32_bf16(av[i], bv[j], acc[i][j], 0, 0, 0);
        __builtin_amdgcn_s_setprio(0);
    }

#pragma unroll
    for (int i = 0; i < 8; ++i) {
#pragma unroll
        for (int r2 = 0; r2 < 4; ++r2) {
            long grow = m0 + wr * 128 + i * 16 + lh * 4 + r2;
            if (FP32OUT && grow >= MStore) continue;
#pragma unroll
            for (int j = 0; j < 4; ++j) {
                int gcol = n0 + wc * 64 + j * 16 + lq;
                if (FP32OUT) {
                    if (gcol < NStore)
                        Cf[grow * ldc + gcol] = acc[i][j][r2] + bias[gcol];
                } else {
                    Cb[grow * ldc + gcol] = f2bf(acc[i][j][r2]);
                }
            }
        }
    }
}

// ---------------- V transpose: qkv v-segment [key][d] -> vtb [b][h][d][KPAD keys], zero-padded ----------------
__global__ __launch_bounds__(256) void v_transpose(const unsigned short* __restrict__ qkv,
                                                   unsigned short* __restrict__ vtb) {
    const int kt = blockIdx.x, h = blockIdx.y, b = blockIdx.z;
    const int t = threadIdx.x;
    __shared__ unsigned short tile[64][136];   // 272B row stride: 16B-aligned, bank-spread

    {
        int r = t >> 2, dq = (t & 3) * 32;
        int key = kt * 64 + r;
        int keyc = key < N_ ? key : N_ - 1;
        const unsigned short* src = qkv + ((long)(b * N_) + keyc) * NQKVP + 2 * C_ + h * D_ + dq;
        short8 a0 = *reinterpret_cast<const short8*>(src);
        short8 a1 = *reinterpret_cast<const short8*>(src + 8);
        short8 a2 = *reinterpret_cast<const short8*>(src + 16);
        short8 a3 = *reinterpret_cast<const short8*>(src + 24);
        if (key >= N_) { a0 = 0; a1 = 0; a2 = 0; a3 = 0; }
        *reinterpret_cast<short8*>(&tile[r][dq])      = a0;
        *reinterpret_cast<short8*>(&tile[r][dq + 8])  = a1;
        *reinterpret_cast<short8*>(&tile[r][dq + 16]) = a2;
        *reinterpret_cast<short8*>(&tile[r][dq + 24]) = a3;
    }
    __syncthreads();
    {
        int d = t >> 1, k0 = (t & 1) * 32;
        unsigned short* dst = vtb + ((long)(b * H_ + h) * D_ + d) * KPAD + kt * 64 + k0;
#pragma unroll
        for (int jj = 0; jj < 4; ++jj) {
            short8 g;
#pragma unroll
            for (int e = 0; e < 8; ++e) g[e] = (short)tile[k0 + jj * 8 + e][d];
            *reinterpret_cast<short8*>(dst + jj * 8) = g;
        }
    }
}

// ---------------- flash attention, swapped-QK design; softmax in exp2 domain.
// 4 waves x 32 q-rows = 128 q/block (r18 optimum: the 8-wave variant was neutral-to-
// negative — wider barrier convergence offsets the halved staging; r19). Tail-tile
// fix: waves with qbase >= N_ skip all compute via a wave-uniform guard but still
// run staging + every barrier in order, preserving the block sync structure.
__global__ __launch_bounds__(256, 2) void attn_fwd(const unsigned short* __restrict__ qkv,
                                                   const unsigned short* __restrict__ vtb,
                                                   unsigned short* __restrict__ outb) {
    const int qt = blockIdx.x, h = blockIdx.y, b = blockIdx.z;
    const int t = threadIdx.x, w = t >> 6, l = t & 63;
    const int lq = l & 15, lh = l >> 4;

    __shared__ unsigned short sK[2][KVB * D_];   // [key][128d], 16 slots/row, swizzled
    __shared__ unsigned short sV[2][D_ * KVB];   // [d][64k],    8 slots/row, swizzled

    const int qbase = qt * 128 + w * 32;
    const bool act = qbase < N_;                 // wave-uniform: any valid q-row in this wave

    // Q fragments (q pre-scaled in rmsnorm)
    bf16x8 qf[2][4];
#pragma unroll
    for (int qg = 0; qg < 2; ++qg) {
        int qrow = qbase + qg * 16 + lq; if (qrow > N_ - 1) qrow = N_ - 1;
        const unsigned short* qp = qkv + (long)(b * N_ + qrow) * NQKVP + h * D_;
#pragma unroll
        for (int ds = 0; ds < 4; ++ds)
            qf[qg][ds] = *reinterpret_cast<const bf16x8*>(qp + ds * 32 + lh * 8);
    }

    // staging source pointers (4 slots each of K and Vt per thread)
    const unsigned short* kp[4];
    const unsigned short* vp[4];
#pragma unroll
    for (int i = 0; i < 4; ++i) {
        int slot = i * 256 + t;
        { int r = slot >> 4, sd = (slot & 15) ^ (r & 7);
          kp[i] = qkv + ((long)(b * N_) + r) * NQKVP + C_ + h * D_ + sd * 8; }
        { int d = slot >> 3, sk = (slot & 7) ^ (d & 7);
          vp[i] = vtb + ((long)(b * H_ + h) * D_ + d) * KPAD + sk * 8; }
    }
    const long kvstep = 64L * NQKVP;

    auto stageK = [&](int tile, int buf) {
        char* dst = (char*)sK[buf];
        if (tile < 16) {
            long off = (long)tile * kvstep;
#pragma unroll
            for (int i = 0; i < 4; ++i) gload_lds16(kp[i] + off, dst + (i * 256 + t) * 16);
        } else {  // tail: all rows read key 1024 (invalid k's masked in softmax)
#pragma unroll
            for (int i = 0; i < 4; ++i) {
                int slot = i * 256 + t;
                int r = slot >> 4, sd = (slot & 15) ^ (r & 7);
                const unsigned short* p = qkv + ((long)(b * N_) + (N_ - 1)) * NQKVP + C_ + h * D_ + sd * 8;
                gload_lds16(p, dst + slot * 16);
            }
        }
    };
    auto stageV = [&](int tile, int buf) {   // Vt zero-padded to KPAD: no tail clamp
        char* dst = (char*)sV[buf];
        long off = (long)tile * 64;
#pragma unroll
        for (int i = 0; i < 4; ++i) gload_lds16(vp[i] + off, dst + (i * 256 + t) * 16);
    };

    f32x4 o[2][8] = {};
    float m[2] = {-1e30f, -1e30f}, lsum[2] = {0.f, 0.f};

    stageK(0, 0); stageV(0, 0);

    for (int tt = 0; tt < 17; ++tt) {
        const int cur = tt & 1;
        if (tt < 16) { stageK(tt + 1, cur ^ 1); stageV(tt + 1, cur ^ 1); }
        if (tt < 16) asm volatile("s_waitcnt vmcnt(8)" ::: "memory");
        else         asm volatile("s_waitcnt vmcnt(0)" ::: "memory");
        __builtin_amdgcn_s_barrier();

        if (act) {
            const unsigned short* bK = sK[cur];
            const unsigned short* bV = sV[cur];

            // S^T[k][q]: 4 chunks of 16 keys; lane holds k = c*16 + 4*lh + r, q = lq
            f32x4 s[2][4] = {};
#pragma unroll
            for (int c = 0; c < 4; ++c) {
                bf16x8 kf[4];
#pragma unroll
                for (int ds = 0; ds < 4; ++ds)
                    kf[ds] = *reinterpret_cast<const bf16x8*>(
                        bK + (c * 16 + lq) * D_ + (((ds << 2) + lh) ^ (lq & 7)) * 8);
                __builtin_amdgcn_s_setprio(1);
#pragma unroll
                for (int qg = 0; qg < 2; ++qg)
#pragma unroll
                    for (int ds = 0; ds < 4; ++ds)
                        s[qg][c] = __builtin_amdgcn_mfma_f32_16x16x32_bf16(kf[ds], qf[qg][ds], s[qg][c], 0, 0, 0);
                __builtin_amdgcn_s_setprio(0);
            }
            if (tt == 16) {   // mask keys >= 1025 (only k_local 0 valid)
#pragma unroll
                for (int c = 0; c < 4; ++c)
#pragma unroll
                    for (int r = 0; r < 4; ++r)
                        if (c * 16 + 4 * lh + r != 0) { s[0][c][r] = -1e30f; s[1][c][r] = -1e30f; }
            }

            bf16x8 pa[2][2];
#pragma unroll
            for (int qg = 0; qg < 2; ++qg) {
                float mx = s[qg][0][0];
#pragma unroll
                for (int c = 0; c < 4; ++c)
#pragma unroll
                    for (int r = 0; r < 4; ++r) mx = fmaxf(mx, s[qg][c][r]);
                mx = fmaxf(mx, __shfl_xor(mx, 16));
                mx = fmaxf(mx, __shfl_xor(mx, 32));
                if (__any(mx - m[qg] > 11.5416f)) {   // T13 defer-rescale (8/ln2, exp2 domain)
                    float mnew = fmaxf(m[qg], mx);
                    float corr = exp2_fast(m[qg] - mnew);
                    lsum[qg] *= corr;
#pragma unroll
                    for (int r = 0; r < 4; ++r) {
                        float co = __shfl(corr, lh * 4 + r);
#pragma unroll
                        for (int nf = 0; nf < 8; ++nf) o[qg][nf][r] *= co;
                    }
                    m[qg] = mnew;
                }
                float p[4][4]; float rs = 0.f;
#pragma unroll
                for (int c = 0; c < 4; ++c)
#pragma unroll
                    for (int r = 0; r < 4; ++r) {
                        p[c][r] = exp2_fast(s[qg][c][r] - m[qg]);
                        rs += p[c][r];
                    }
                rs += __shfl_xor(rs, 16);
                rs += __shfl_xor(rs, 32);
                lsum[qg] += rs;
#pragma unroll
                for (int h2 = 0; h2 < 2; ++h2) {
                    unsigned A0 = cvtpk_bf16(p[2 * h2][0], p[2 * h2][1]);
                    unsigned A1 = cvtpk_bf16(p[2 * h2][2], p[2 * h2][3]);
                    unsigned B0 = cvtpk_bf16(p[2 * h2 + 1][0], p[2 * h2 + 1][1]);
                    unsigned B1 = cvtpk_bf16(p[2 * h2 + 1][2], p[2 * h2 + 1][3]);
                    const bool lo2 = lh < 2, odd = lh & 1;
                    unsigned x16_0 = __shfl_xor(lo2 ? A0 : B0, 16);
                    unsigned x16_1 = __shfl_xor(lo2 ? A1 : B1, 16);
                    unsigned x32_0 = __shfl_xor(lo2 ? B0 : A0, 32);
                    unsigned x32_1 = __shfl_xor(lo2 ? B1 : A1, 32);
                    unsigned x48_0 = __shfl_xor(odd ? B0 : A0, 48);
                    unsigned x48_1 = __shfl_xor(odd ? B1 : A1, 48);
                    unsigned w0 = lh == 0 ? A0 : lh == 1 ? x48_0 : lh == 2 ? x32_0 : x16_0;
                    unsigned w1 = lh == 0 ? A1 : lh == 1 ? x48_1 : lh == 2 ? x32_1 : x16_1;
                    unsigned w2 = lh == 0 ? x16_0 : lh == 1 ? x32_0 : lh == 2 ? x48_0 : B0;
                    unsigned w3 = lh == 0 ? x16_1 : lh == 1 ? x32_1 : lh == 2 ? x48_1 : B1;
                    u32x4 wv = {w0, w1, w2, w3};
                    pa[qg][h2] = __builtin_bit_cast(bf16x8, wv);
                }
            }

            // PV: o[q][d] += P[q][k] * Vt[d][k]
#pragma unroll
            for (int h2 = 0; h2 < 2; ++h2) {
                bf16x8 vf[8];
#pragma unroll
                for (int nf = 0; nf < 8; ++nf)
                    vf[nf] = *reinterpret_cast<const bf16x8*>(
                        bV + (nf * 16 + lq) * KVB + (((h2 << 2) + lh) ^ (lq & 7)) * 8);
                __builtin_amdgcn_s_setprio(1);
#pragma unroll
                for (int qg = 0; qg < 2; ++qg)
#pragma unroll
                    for (int nf = 0; nf < 8; ++nf)
                        o[qg][nf] = __builtin_amdgcn_mfma_f32_16x16x32_bf16(pa[qg][h2], vf[nf], o[qg][nf], 0, 0, 0);
                __builtin_amdgcn_s_setprio(0);
            }
        }
        __builtin_amdgcn_s_barrier();
    }

    // epilogue: normalize by lsum and store
    if (act) {
#pragma unroll
        for (int qg = 0; qg < 2; ++qg) {
            float linv = 1.f / lsum[qg];
#pragma unroll
            for (int r = 0; r < 4; ++r) {
                float li = __shfl(linv, lh * 4 + r);
                int row = qbase + qg * 16 + 4 * lh + r;
                if (row < N_) {
                    unsigned short* dst = outb + (long)(b * N_ + row) * C_ + h * D_ + lq;
#pragma unroll
                    for (int nf = 0; nf < 8; ++nf)
                        dst[nf * 16] = f2bf(o[qg][nf][r] * li);
                }
            }
        }
    }
}

extern "C" void kernel_launch(void* const* d_in, const int* in_sizes, int n_in,
                              void* d_out, int out_size, void* d_ws, size_t ws_size,
                              hipStream_t stream) {
    (void)in_sizes; (void)n_in; (void)out_size; (void)ws_size;
    const float* x   = (const float*)d_in[0];
    const float* wq  = (const float*)d_in[1];
    const float* qnw = (const float*)d_in[2];
    const float* knw = (const float*)d_in[3];
    const float* wp  = (const float*)d_in[4];
    const float* bp  = (const float*)d_in[5];
    float* out = (float*)d_out;

    // workspace layout (bf16 buffers), ~356 MB
    unsigned short* xb    = (unsigned short*)d_ws;                 // M_PAD x C
    unsigned short* wqb   = xb   + (size_t)M_PAD * C_;             // NQKVP x C (dead after GEMM1)
    unsigned short* wpb   = wqb  + (size_t)NQKVP * C_;             // CPADW x C (rows >= 3200 zero)
    unsigned short* qkvb  = wpb  + (size_t)CPADW * C_;             // M_PAD x NQKVP
    unsigned short* attnb = qkvb + (size_t)M_PAD * NQKVP;          // M_PAD x C
    unsigned short* vtb   = wqb;   // V^T [B][H][D][KPAD] = 55.7 MB, aliases dead wqb (62.3 MB)

    auto cvt = [&](const float* s, unsigned short* d, long nsrc, long ntot) {
        int blocks = (int)((ntot / 4 + 255) / 256);
        convert_pad<<<blocks, 256, 0, stream>>>(s, d, nsrc, ntot);
    };
    cvt(x,  xb,  (long)M_REAL * C_, (long)M_PAD * C_);
    cvt(wq, wqb, (long)NQKV * C_,   (long)NQKVP * C_);
    cvt(wp, wpb, (long)C_ * C_,     (long)CPADW * C_);
    cvt(x, attnb + (size_t)M_REAL * C_, 0, (long)(M_PAD - M_REAL) * C_);  // zero pad rows

    // GEMM1: qkv = x * w_qkv^T  (M=8448, Ncols=9728, K=3200)
    gemm_pipe<0><<<(M_PAD / 256) * (NQKVP / 256), 512, 0, stream>>>(
        xb, wqb, qkvb, nullptr, nullptr, C_, M_PAD / 256, NQKVP / 256, NQKVP, M_PAD, NQKVP);

    rmsnorm_qk<<<dim3(M_REAL, 2), 256, 0, stream>>>(qkvb, qnw, knw);

    v_transpose<<<dim3(17, H_, B_), 256, 0, stream>>>(qkvb, vtb);

    attn_fwd<<<dim3(9, H_, B_), 256, 0, stream>>>(qkvb, vtb, attnb);

    // GEMM2: out = attn * w_proj^T + b  (M=8448->8200, Ncols=3328->3200, K=3200)
    gemm_pipe<1><<<(M_PAD / 256) * (CPADW / 256), 512, 0, stream>>>(
        attnb, wpb, nullptr, out, bp, C_, M_PAD / 256, CPADW / 256, C_, M_REAL, C_);
}